// Round 2
// baseline (980.864 us; speedup 1.0000x reference)
//
#include <hip/hip_runtime.h>

// ---------------------------------------------------------------------------
// Attention_89361089560777: B=8, S=1024, H=768, nh=12, d=64
// Pipeline: prep_weights, prep_h -> qkv_gemm(128x128,m97) -> vtrans ->
//           attn (K-SPLIT x2, swapped-QKT in-register softmax, x16 PV) ->
//           kmerge -> out_gemm
// R2: grid was 512 blocks = 2/CU (23% occupancy, latency-bound, HBM duty 20%).
//     K-split doubles blocks to 1024 = 4/CU; Sc LDS removed via swapped QK^T
//     (S^T in regs, q=lane&15) + PV with mfma_16x16x16 whose B-frag matches
//     the S^T fragment layout; bias+mask staged in ONE 26.6KB slab (ASYNC16,
//     XOR-swizzled, warp-packed b96/b64 reads). fp32 partials + merge.
// ---------------------------------------------------------------------------

typedef __attribute__((ext_vector_type(8))) __bf16 bf16x8;
typedef __attribute__((ext_vector_type(4))) __bf16 bf16x4;
typedef __attribute__((ext_vector_type(4))) float floatx4;
typedef __attribute__((ext_vector_type(4))) short short4v;
using bf16 = __bf16;

#define HID 768
#define NHEAD 12
#define DHEAD 64
#define SEQ 1024
#define NBATCH 8
#define WELEM (HID * HID)                      // 589824
#define QKVELEM (NBATCH * NHEAD * SEQ * DHEAD) // 6291456
#define OPELEM QKVELEM                         // fp32 partial O per ks
#define MLROWS (NBATCH * NHEAD * SEQ)          // 98304

__device__ __forceinline__ floatx4 mfma_bf16(bf16x8 a, bf16x8 b, floatx4 c) {
  return __builtin_amdgcn_mfma_f32_16x16x32_bf16(a, b, c, 0, 0, 0);
}

// 16x16x16 bf16 MFMA: B-frag k-layout (k = quad*4+j) matches the 16x16 C-frag
// row layout, so S^T fragments feed PV directly with zero data movement.
__device__ __forceinline__ floatx4 mfma16_bf16(bf16x4 a, bf16x4 b, floatx4 c) {
#if __has_builtin(__builtin_amdgcn_mfma_f32_16x16x16bf16_1k)
  return __builtin_amdgcn_mfma_f32_16x16x16bf16_1k(
      __builtin_bit_cast(short4v, a), __builtin_bit_cast(short4v, b), c, 0, 0, 0);
#else
  floatx4 d = c;
  asm volatile("s_nop 1\n\tv_mfma_f32_16x16x16_bf16 %0, %1, %2, %0\n\ts_nop 4"
               : "+v"(d) : "v"(a), "v"(b));
  return d;
#endif
}

// async global->LDS, 16B per lane; LDS dest must be wave-uniform base + lane*16
#define ASYNC16(gp, lp)                                           \
  __builtin_amdgcn_global_load_lds(                               \
      (__attribute__((address_space(1))) void*)(gp),              \
      (__attribute__((address_space(3))) void*)(lp), 16, 0, 0)

// ---------------------------------------------------------------------------
// Weight prep: WT[m][n][k] = bf16(W_m[k][n])
// ---------------------------------------------------------------------------
__global__ void prep_weights(const float* __restrict__ Wq, const float* __restrict__ Wk,
                             const float* __restrict__ Wv, const float* __restrict__ Wo,
                             bf16* __restrict__ WT) {
  __shared__ float t[32][33];
  const int m = blockIdx.z;
  const float* W = (m == 0) ? Wq : (m == 1) ? Wk : (m == 2) ? Wv : Wo;
  const int k0 = blockIdx.x * 32, n0 = blockIdx.y * 32;
  const int tx = threadIdx.x, ty = threadIdx.y;
#pragma unroll
  for (int i = 0; i < 4; ++i)
    t[ty + 8 * i][tx] = W[(size_t)(k0 + ty + 8 * i) * HID + n0 + tx];
  __syncthreads();
  bf16* o = WT + (size_t)m * WELEM;
#pragma unroll
  for (int i = 0; i < 4; ++i)
    o[(size_t)(n0 + ty + 8 * i) * HID + k0 + tx] = (bf16)t[tx][ty + 8 * i];
}

// h (fp32) -> hb (bf16), 8 elems/thread
__global__ void prep_h(const float* __restrict__ X, bf16* __restrict__ Y) {
  const size_t i = ((size_t)blockIdx.x * 256 + threadIdx.x) * 8;
  float4 a = *(const float4*)(X + i);
  float4 b = *(const float4*)(X + i + 4);
  bf16x8 o;
  o[0] = (bf16)a.x; o[1] = (bf16)a.y; o[2] = (bf16)a.z; o[3] = (bf16)a.w;
  o[4] = (bf16)b.x; o[5] = (bf16)b.y; o[6] = (bf16)b.z; o[7] = (bf16)b.w;
  *(bf16x8*)(Y + i) = o;
}

// ---------------------------------------------------------------------------
// QKV GEMM, m97 structure: 128x128 tile, BK=32, global_load_lds w16.
// ---------------------------------------------------------------------------
__launch_bounds__(256, 2)
__global__ void qkv_gemm(const bf16* __restrict__ A, const bf16* __restrict__ WT,
                         const float* __restrict__ bq, const float* __restrict__ bk,
                         const float* __restrict__ bv,
                         bf16* __restrict__ Qb, bf16* __restrict__ Kb,
                         bf16* __restrict__ Vb) {
  __shared__ __align__(16) bf16 As[128][32];
  __shared__ __align__(16) bf16 Bs[128][32];
  const int mat = blockIdx.z;
  const int bn = blockIdx.x * 128, bm = blockIdx.y * 128;
  const bf16* W = WT + (size_t)mat * WELEM;
  const int tid = threadIdx.x, lane = tid & 63, warp = tid >> 6;
  const int fr = lane & 15, quad = lane >> 4;
  const int wr = warp >> 1, wc = warp & 1;

  floatx4 acc[4][4] = {};

  const int srow = tid >> 2, scol = (tid & 3) * 8;
  const bf16* as0 = A + (size_t)(bm + srow) * HID + scol;
  const bf16* as1 = A + (size_t)(bm + 64 + srow) * HID + scol;
  const bf16* bs0 = W + (size_t)(bn + srow) * HID + scol;
  const bf16* bs1 = W + (size_t)(bn + 64 + srow) * HID + scol;
  bf16* la0 = &As[srow][scol];
  bf16* la1 = &As[64 + srow][scol];
  bf16* lb0 = &Bs[srow][scol];
  bf16* lb1 = &Bs[64 + srow][scol];

  for (int k0 = 0; k0 < HID; k0 += 32) {
    ASYNC16(as0 + k0, la0);
    ASYNC16(as1 + k0, la1);
    ASYNC16(bs0 + k0, lb0);
    ASYNC16(bs1 + k0, lb1);
    __syncthreads();
    bf16x8 a[4], b[4];
#pragma unroll
    for (int mi = 0; mi < 4; ++mi) a[mi] = *(const bf16x8*)&As[wr * 64 + mi * 16 + fr][quad * 8];
#pragma unroll
    for (int ni = 0; ni < 4; ++ni) b[ni] = *(const bf16x8*)&Bs[wc * 64 + ni * 16 + fr][quad * 8];
#pragma unroll
    for (int mi = 0; mi < 4; ++mi)
#pragma unroll
      for (int ni = 0; ni < 4; ++ni) acc[mi][ni] = mfma_bf16(a[mi], b[ni], acc[mi][ni]);
    __syncthreads();
  }

  const float* bias = (mat == 0) ? bq : (mat == 1) ? bk : bv;
#pragma unroll
  for (int mi = 0; mi < 4; ++mi)
#pragma unroll
    for (int ni = 0; ni < 4; ++ni)
#pragma unroll
      for (int r = 0; r < 4; ++r) {
        const int grow = bm + wr * 64 + mi * 16 + quad * 4 + r;
        const int gcol = bn + wc * 64 + ni * 16 + fr;
        float v = acc[mi][ni][r] + bias[gcol];
        const int bb = grow >> 10, ss = grow & 1023;
        const int head = gcol >> 6, dc = gcol & 63;
        const size_t bh = (size_t)bb * NHEAD + head;
        const size_t idx = (bh * SEQ + ss) * DHEAD + dc;
        if (mat == 0) Qb[idx] = (bf16)(v * 0.125f);
        else if (mat == 1) Kb[idx] = (bf16)v;
        else Vb[idx] = (bf16)v;
      }
}

// ---------------------------------------------------------------------------
// V transpose: Vb [bh][s][d] -> Vt [bh][d][s], 64x64 LDS tiles
// ---------------------------------------------------------------------------
__global__ void vtrans(const bf16* __restrict__ Vb, bf16* __restrict__ Vt) {
  __shared__ bf16 t[64][72];
  const int st = blockIdx.x, bh = blockIdx.y;
  const int tid = threadIdx.x;
  const bf16* src = Vb + ((size_t)bh * SEQ + st * 64) * DHEAD;
#pragma unroll
  for (int p = 0; p < 2; ++p) {
    const int r = p * 32 + (tid >> 3), c = (tid & 7) * 8;
    *(bf16x8*)&t[r][c] = *(const bf16x8*)(src + (size_t)r * DHEAD + c);
  }
  __syncthreads();
#pragma unroll
  for (int p = 0; p < 2; ++p) {
    const int d = p * 32 + (tid >> 3), s0 = (tid & 7) * 8;
    bf16x8 o;
#pragma unroll
    for (int k = 0; k < 8; ++k) o[k] = t[s0 + k][d];
    *(bf16x8*)(Vt + ((size_t)bh * DHEAD + d) * SEQ + st * 64 + s0) = o;
  }
}

// ---------------------------------------------------------------------------
// Attention, k-split: block = (qt, b, ks). 16 q-rows, ALL 12 heads (3/wave),
// k-chunks of 32 over ks's half of the sequence. Single 26.6KB LDS slab
// (bias [16q][32c][12h] f32 + mask [16][32] i32) staged via ASYNC16 with
// XOR-swizzled 16B units; 2 barriers/chunk; cross-block overlap (4 blocks/CU).
// Swapped QK^T -> S^T in regs (q = lane&15); softmax in-register;
// PV via mfma_16x16x16 (B-frag == S^T frag layout). Unnormalized fp32
// partial O^T + (m,l) written per ks; kmerge combines.
// ---------------------------------------------------------------------------
__launch_bounds__(256, 4)
__global__ void attn_kernel(const bf16* __restrict__ Qb, const bf16* __restrict__ Kb,
                            const bf16* __restrict__ Vt, const float* __restrict__ bias,
                            const int* __restrict__ maskp,
                            float* __restrict__ Op, float2* __restrict__ Ml) {
  __shared__ __align__(16) float4 BbU[1536]; // bias slab, 24 KB
  __shared__ __align__(16) int4  MbU[128];   // mask slab, 2 KB

  const int qt = blockIdx.x, b = blockIdx.y, ks = blockIdx.z;
  const int tid = threadIdx.x, lane = tid & 63, warp = tid >> 6;
  const int fr = lane & 15, quad = lane >> 4;
  const size_t brow = (size_t)b * SEQ + qt * 16;

  float* Opk = Op + (size_t)ks * OPELEM;
  float2* Mlk = Ml + (size_t)ks * MLROWS;

  // Q fragments for this wave's 3 heads (pre-scaled by 1/8 in qkv_gemm)
  bf16x8 qa0[3], qa1[3];
#pragma unroll
  for (int j = 0; j < 3; ++j) {
    const size_t bh = (size_t)b * NHEAD + 3 * warp + j;
    const bf16* Qp = Qb + (bh * SEQ + qt * 16) * DHEAD;
    qa0[j] = *(const bf16x8*)(Qp + fr * DHEAD + quad * 8);
    qa1[j] = *(const bf16x8*)(Qp + fr * DHEAD + 32 + quad * 8);
  }

  // staging sources (per thread, chunk-invariant): bias 6 units, mask 1 unit
  const float4* bias4 = (const float4*)bias;
  const float4* bsrc[6];
#pragma unroll
  for (int i = 0; i < 6; ++i) {
    const int f = tid + 256 * i, q = f / 96, rl = f % 96;
    const int rg = (rl & ~7) | ((rl ^ q) & 7);  // XOR-swizzled global unit
    bsrc[i] = bias4 + ((size_t)(brow + q) * SEQ) * 3 + rg;
  }
  const int4* msrc = nullptr;
  if (tid < 128) {
    const int q = tid >> 3, s = tid & 7;
    msrc = (const int4*)(maskp + (size_t)(brow + q) * SEQ) + (s ^ (q & 7));
  }

  float mrun[3] = {-1e30f, -1e30f, -1e30f};
  float lrun[3] = {0.f, 0.f, 0.f};
  floatx4 oaccT[3][4] = {};

  for (int ch = 0; ch < 16; ++ch) {
    const int c0 = (ks * 16 + ch) * 32;

    // ---- stage bias+mask slab for this chunk (readers of prev chunk are done) ----
#pragma unroll
    for (int i = 0; i < 6; ++i) ASYNC16(bsrc[i] + c0 * 3, BbU + tid + 256 * i);
    if (tid < 128) ASYNC16(msrc + c0 / 4, MbU + tid);
    __syncthreads();  // vmcnt drain: slab ready

    // ---- swapped QK^T: st[j][ct][r] = S[q=fr][k = c0 + ct*16 + quad*4 + r] ----
    floatx4 st[3][2];
#pragma unroll
    for (int j = 0; j < 3; ++j) {
      const size_t bh = (size_t)b * NHEAD + 3 * warp + j;
#pragma unroll
      for (int ct = 0; ct < 2; ++ct) {
        const bf16* kp = Kb + (bh * SEQ + c0 + ct * 16 + fr) * DHEAD;
        bf16x8 k0 = *(const bf16x8*)(kp + quad * 8);
        bf16x8 k1 = *(const bf16x8*)(kp + 32 + quad * 8);
        floatx4 t = {0.f, 0.f, 0.f, 0.f};
        t = mfma_bf16(k0, qa0[j], t);
        t = mfma_bf16(k1, qa1[j], t);
        st[j][ct] = t;
      }
    }

    // ---- bias (warp-packed reads) + mask, in place into st ----
    const float* Bf = (const float*)BbU;
#pragma unroll
    for (int ct = 0; ct < 2; ++ct) {
      const int4 m4 = MbU[fr * 8 + ((ct * 4 + quad) ^ (fr & 7))];
      const int mm[4] = {m4.x, m4.y, m4.z, m4.w};
#pragma unroll
      for (int r = 0; r < 4; ++r) {
        const int ug = 3 * (ct * 16 + quad * 4 + r);
        const int u0 = fr * 96 + ((ug & ~7) | ((ug ^ fr) & 7));
        const int u1 = fr * 96 + (((ug + 1) & ~7) | (((ug + 1) ^ fr) & 7));
        const int u2 = fr * 96 + (((ug + 2) & ~7) | (((ug + 2) ^ fr) & 7));
        float b0, b1, b2;
        if (warp == 0)      { const float* p = Bf + 4 * u0; b0 = p[0]; b1 = p[1]; b2 = p[2]; }
        else if (warp == 1) { const float* p = Bf + 4 * u1; b0 = Bf[4 * u0 + 3]; b1 = p[0]; b2 = p[1]; }
        else if (warp == 2) { const float* p = Bf + 4 * u1; b0 = p[2]; b1 = p[3]; b2 = Bf[4 * u2]; }
        else                { const float* p = Bf + 4 * u2; b0 = p[1]; b1 = p[2]; b2 = p[3]; }
        if (mm[r]) {
          st[0][ct][r] = 0.f; st[1][ct][r] = 0.f; st[2][ct][r] = 0.f;
        } else {
          st[0][ct][r] += b0; st[1][ct][r] += b1; st[2][ct][r] += b2;
        }
      }
    }

    // ---- per-head in-register online softmax + PV (x16 MFMA) ----
#pragma unroll
    for (int j = 0; j < 3; ++j) {
      float s8[8];
#pragma unroll
      for (int ct = 0; ct < 2; ++ct)
#pragma unroll
        for (int r = 0; r < 4; ++r) s8[ct * 4 + r] = st[j][ct][r];
      float mx = mrun[j];
#pragma unroll
      for (int k = 0; k < 8; ++k) mx = fmaxf(mx, s8[k]);
      mx = fmaxf(mx, __shfl_xor(mx, 16));
      mx = fmaxf(mx, __shfl_xor(mx, 32));
      const float alpha = __expf(mrun[j] - mx);
      float e[8], sum = 0.f;
#pragma unroll
      for (int k = 0; k < 8; ++k) { e[k] = __expf(s8[k] - mx); sum += e[k]; }
      sum += __shfl_xor(sum, 16);
      sum += __shfl_xor(sum, 32);
      lrun[j] = lrun[j] * alpha + sum;
      mrun[j] = mx;
      bf16x4 pa0, pa1;
#pragma unroll
      for (int r = 0; r < 4; ++r) { pa0[r] = (bf16)e[r]; pa1[r] = (bf16)e[4 + r]; }
#pragma unroll
      for (int dvt = 0; dvt < 4; ++dvt)
#pragma unroll
        for (int r = 0; r < 4; ++r) oaccT[j][dvt][r] *= alpha;
      const size_t bh = (size_t)b * NHEAD + 3 * warp + j;
#pragma unroll
      for (int dvt = 0; dvt < 4; ++dvt) {
        const bf16* vp = Vt + (bh * DHEAD + dvt * 16 + fr) * SEQ + c0 + quad * 4;
        bf16x4 v0 = *(const bf16x4*)vp;
        bf16x4 v1 = *(const bf16x4*)(vp + 16);
        oaccT[j][dvt] = mfma16_bf16(v0, pa0, oaccT[j][dvt]);
        oaccT[j][dvt] = mfma16_bf16(v1, pa1, oaccT[j][dvt]);
      }
    }

    __syncthreads();  // all waves done reading slab -> next stage may overwrite
  }

  // ---- epilogue: unnormalized O^T partial (fp32) + (m,l) ----
#pragma unroll
  for (int j = 0; j < 3; ++j) {
    const int hh = 3 * warp + j;
    const size_t row = ((size_t)b * NHEAD + hh) * SEQ + qt * 16 + fr;
#pragma unroll
    for (int dvt = 0; dvt < 4; ++dvt)
      *(floatx4*)(Opk + row * DHEAD + dvt * 16 + quad * 4) = oaccT[j][dvt];
    if (quad == 0) Mlk[row] = make_float2(mrun[j], lrun[j]);
  }
}

// ---------------------------------------------------------------------------
// Merge the 2 k-split partials: O = sum(O~_ks * e^{m_ks-M}) / sum(l_ks * e^{m_ks-M})
// One row = (bh, s); 16 threads/row, float4 over d.
// ---------------------------------------------------------------------------
__global__ void kmerge(const float* __restrict__ O0, const float* __restrict__ O1,
                       const float2* __restrict__ ml0, const float2* __restrict__ ml1,
                       bf16* __restrict__ Ob) {
  const int t = blockIdx.x * 256 + threadIdx.x;
  const int row = t >> 4;
  const int dq = (t & 15) * 4;
  const float2 a = ml0[row], c = ml1[row];
  const float M = fmaxf(a.x, c.x);
  const float w0 = __expf(a.x - M), w1 = __expf(c.x - M);
  const float inv = 1.0f / (a.y * w0 + c.y * w1);
  floatx4 o0 = *(const floatx4*)(O0 + (size_t)row * DHEAD + dq);
  floatx4 o1 = *(const floatx4*)(O1 + (size_t)row * DHEAD + dq);
  const int bh = row >> 10, s = row & 1023;
  const int bb = bh / NHEAD, hh = bh % NHEAD;
  bf16x4 o;
#pragma unroll
  for (int r = 0; r < 4; ++r) o[r] = (bf16)((o0[r] * w0 + o1[r] * w1) * inv);
  *(bf16x4*)(Ob + ((size_t)bb * SEQ + s) * HID + hh * DHEAD + dq) = o;
}

// ---------------------------------------------------------------------------
// Output projection, m97 structure: out = Ob @ Wo + bo (fp32)
// ---------------------------------------------------------------------------
__launch_bounds__(256, 2)
__global__ void out_gemm(const bf16* __restrict__ A, const bf16* __restrict__ W,
                         const float* __restrict__ bo, float* __restrict__ out) {
  __shared__ __align__(16) bf16 As[128][32];
  __shared__ __align__(16) bf16 Bs[128][32];
  const int bn = blockIdx.x * 128, bm = blockIdx.y * 128;
  const int tid = threadIdx.x, lane = tid & 63, warp = tid >> 6;
  const int fr = lane & 15, quad = lane >> 4;
  const int wr = warp >> 1, wc = warp & 1;

  floatx4 acc[4][4] = {};

  const int srow = tid >> 2, scol = (tid & 3) * 8;
  const bf16* as0 = A + (size_t)(bm + srow) * HID + scol;
  const bf16* as1 = A + (size_t)(bm + 64 + srow) * HID + scol;
  const bf16* bs0 = W + (size_t)(bn + srow) * HID + scol;
  const bf16* bs1 = W + (size_t)(bn + 64 + srow) * HID + scol;
  bf16* la0 = &As[srow][scol];
  bf16* la1 = &As[64 + srow][scol];
  bf16* lb0 = &Bs[srow][scol];
  bf16* lb1 = &Bs[64 + srow][scol];

  for (int k0 = 0; k0 < HID; k0 += 32) {
    ASYNC16(as0 + k0, la0);
    ASYNC16(as1 + k0, la1);
    ASYNC16(bs0 + k0, lb0);
    ASYNC16(bs1 + k0, lb1);
    __syncthreads();
    bf16x8 a[4], b[4];
#pragma unroll
    for (int mi = 0; mi < 4; ++mi) a[mi] = *(const bf16x8*)&As[wr * 64 + mi * 16 + fr][quad * 8];
#pragma unroll
    for (int ni = 0; ni < 4; ++ni) b[ni] = *(const bf16x8*)&Bs[wc * 64 + ni * 16 + fr][quad * 8];
#pragma unroll
    for (int mi = 0; mi < 4; ++mi)
#pragma unroll
      for (int ni = 0; ni < 4; ++ni) acc[mi][ni] = mfma_bf16(a[mi], b[ni], acc[mi][ni]);
    __syncthreads();
  }

#pragma unroll
  for (int mi = 0; mi < 4; ++mi)
#pragma unroll
    for (int ni = 0; ni < 4; ++ni)
#pragma unroll
      for (int r = 0; r < 4; ++r) {
        const int grow = bm + wr * 64 + mi * 16 + quad * 4 + r;
        const int gcol = bn + wc * 64 + ni * 16 + fr;
        out[(size_t)grow * HID + gcol] = acc[mi][ni][r] + bo[gcol];
      }
}

// ---------------------------------------------------------------------------
extern "C" void kernel_launch(void* const* d_in, const int* in_sizes, int n_in,
                              void* d_out, int out_size, void* d_ws, size_t ws_size,
                              hipStream_t stream) {
  const float* h  = (const float*)d_in[0];
  const float* ab = (const float*)d_in[1];
  const int*   mk = (const int*)d_in[2];
  const float* Wq = (const float*)d_in[3];
  const float* bq = (const float*)d_in[4];
  const float* Wk = (const float*)d_in[5];
  const float* bk = (const float*)d_in[6];
  const float* Wv = (const float*)d_in[7];
  const float* bv = (const float*)d_in[8];
  const float* Wo = (const float*)d_in[9];
  const float* bo = (const float*)d_in[10];
  float* out = (float*)d_out;

  // ws: bf16 region [ WT(4W) | hb | Qb | Kb | Vb | Vt ] then fp32 partials.
  bf16* WT = (bf16*)d_ws;
  bf16* hb = WT + (size_t)4 * WELEM;
  bf16* Qb = hb + (size_t)QKVELEM;
  bf16* Kb = Qb + (size_t)QKVELEM;
  bf16* Vb = Kb + (size_t)QKVELEM;
  bf16* Vt = Vb + (size_t)QKVELEM;
  bf16* Ob = Vb;  // reuse (dead after vtrans)
  float* Opw = (float*)(Vt + (size_t)QKVELEM);       // 2 * OPELEM fp32
  float2* Mlw = (float2*)(Opw + (size_t)2 * OPELEM); // 2 * MLROWS float2

  prep_weights<<<dim3(24, 24, 4), dim3(32, 8), 0, stream>>>(Wq, Wk, Wv, Wo, WT);
  prep_h<<<3072, 256, 0, stream>>>(h, hb);
  qkv_gemm<<<dim3(6, 64, 3), 256, 0, stream>>>(hb, WT, bq, bk, bv, Qb, Kb, Vb);
  vtrans<<<dim3(16, 96), 256, 0, stream>>>(Vb, Vt);
  attn_kernel<<<dim3(64, 8, 2), 256, 0, stream>>>(Qb, Kb, Vt, ab, mk, Opw, Mlw);
  kmerge<<<6144, 256, 0, stream>>>(Opw, Opw + OPELEM, Mlw, Mlw + MLROWS, Ob);
  out_gemm<<<dim3(6, 64), 256, 0, stream>>>(Ob, WT + (size_t)3 * WELEM, bo, out);
}

// Round 4
// 798.600 us; speedup vs baseline: 1.2282x; 1.2282x over previous
//
#include <hip/hip_runtime.h>

// ---------------------------------------------------------------------------
// Attention_89361089560777: B=8, S=1024, H=768, nh=12, d=64
// Pipeline: prep_weights, prep_h, maskpack -> qkv_gemm -> vtrans(pack) ->
//           attn (head-group split, dbuf ASYNC16 bias, bitmask, in-reg softmax)
//           -> out_gemm
// R4: resubmission of R3 (container-level infra failure, no counters; kernel
//     audit found no hang/fault path and all mechanisms ran in R1/R2).
//     Structure: 3-way HEAD split (no partials), 6 blocks/CU, XCD-pinned
//     batches (blk%8==b), issue-next->compute->barrier double-buffer,
//     bit-packed mask staged once, XOR-swizzled bias LDS (2-way banks),
//     V packed for single-load x16 PV.
// ---------------------------------------------------------------------------

typedef __attribute__((ext_vector_type(8))) __bf16 bf16x8;
typedef __attribute__((ext_vector_type(4))) __bf16 bf16x4;
typedef __attribute__((ext_vector_type(4))) float floatx4;
typedef __attribute__((ext_vector_type(4))) short short4v;
using bf16 = __bf16;

#define HID 768
#define NHEAD 12
#define DHEAD 64
#define SEQ 1024
#define NBATCH 8
#define WELEM (HID * HID)                      // 589824
#define QKVELEM (NBATCH * NHEAD * SEQ * DHEAD) // 6291456

__device__ __forceinline__ floatx4 mfma_bf16(bf16x8 a, bf16x8 b, floatx4 c) {
  return __builtin_amdgcn_mfma_f32_16x16x32_bf16(a, b, c, 0, 0, 0);
}

// 16x16x16 bf16 MFMA: B-frag k-layout (k = quad*4+r) matches the 16x16 C-frag
// row layout, so S^T fragments feed PV directly with zero data movement.
__device__ __forceinline__ floatx4 mfma16_bf16(bf16x4 a, bf16x4 b, floatx4 c) {
#if __has_builtin(__builtin_amdgcn_mfma_f32_16x16x16bf16_1k)
  return __builtin_amdgcn_mfma_f32_16x16x16bf16_1k(
      __builtin_bit_cast(short4v, a), __builtin_bit_cast(short4v, b), c, 0, 0, 0);
#else
  floatx4 d = c;
  asm volatile("s_nop 1\n\tv_mfma_f32_16x16x16_bf16 %0, %1, %2, %0\n\ts_nop 4"
               : "+v"(d) : "v"(a), "v"(b));
  return d;
#endif
}

// async global->LDS, 16B per lane; LDS dest must be wave-uniform base + lane*16
#define ASYNC16(gp, lp)                                           \
  __builtin_amdgcn_global_load_lds(                               \
      (__attribute__((address_space(1))) void*)(gp),              \
      (__attribute__((address_space(3))) void*)(lp), 16, 0, 0)

// ---------------------------------------------------------------------------
// Weight prep: WT[m][n][k] = bf16(W_m[k][n])
// ---------------------------------------------------------------------------
__global__ void prep_weights(const float* __restrict__ Wq, const float* __restrict__ Wk,
                             const float* __restrict__ Wv, const float* __restrict__ Wo,
                             bf16* __restrict__ WT) {
  __shared__ float t[32][33];
  const int m = blockIdx.z;
  const float* W = (m == 0) ? Wq : (m == 1) ? Wk : (m == 2) ? Wv : Wo;
  const int k0 = blockIdx.x * 32, n0 = blockIdx.y * 32;
  const int tx = threadIdx.x, ty = threadIdx.y;
#pragma unroll
  for (int i = 0; i < 4; ++i)
    t[ty + 8 * i][tx] = W[(size_t)(k0 + ty + 8 * i) * HID + n0 + tx];
  __syncthreads();
  bf16* o = WT + (size_t)m * WELEM;
#pragma unroll
  for (int i = 0; i < 4; ++i)
    o[(size_t)(n0 + ty + 8 * i) * HID + k0 + tx] = (bf16)t[tx][ty + 8 * i];
}

// h (fp32) -> hb (bf16), 8 elems/thread
__global__ void prep_h(const float* __restrict__ X, bf16* __restrict__ Y) {
  const size_t i = ((size_t)blockIdx.x * 256 + threadIdx.x) * 8;
  float4 a = *(const float4*)(X + i);
  float4 b = *(const float4*)(X + i + 4);
  bf16x8 o;
  o[0] = (bf16)a.x; o[1] = (bf16)a.y; o[2] = (bf16)a.z; o[3] = (bf16)a.w;
  o[4] = (bf16)b.x; o[5] = (bf16)b.y; o[6] = (bf16)b.z; o[7] = (bf16)b.w;
  *(bf16x8*)(Y + i) = o;
}

// ---------------------------------------------------------------------------
// Mask bit-pack: mask int32 [8][1024][1024] -> Mbits uint32 [8192 rows][32 words]
// thread t packs 32 ints starting at mp + t*32 (fully linear).
// ---------------------------------------------------------------------------
__global__ void maskpack(const int* __restrict__ mp, unsigned int* __restrict__ Mb) {
  const size_t t = (size_t)blockIdx.x * 256 + threadIdx.x;
  const int4* src = (const int4*)(mp + t * 32);
  unsigned int bits = 0u;
#pragma unroll
  for (int i = 0; i < 8; ++i) {
    int4 m = src[i];
    bits |= (m.x ? 1u : 0u) << (4 * i);
    bits |= (m.y ? 1u : 0u) << (4 * i + 1);
    bits |= (m.z ? 1u : 0u) << (4 * i + 2);
    bits |= (m.w ? 1u : 0u) << (4 * i + 3);
  }
  Mb[t] = bits;
}

// ---------------------------------------------------------------------------
// QKV GEMM, m97 structure: 128x128 tile, BK=32, global_load_lds w16.
// ---------------------------------------------------------------------------
__launch_bounds__(256, 2)
__global__ void qkv_gemm(const bf16* __restrict__ A, const bf16* __restrict__ WT,
                         const float* __restrict__ bq, const float* __restrict__ bk,
                         const float* __restrict__ bv,
                         bf16* __restrict__ Qb, bf16* __restrict__ Kb,
                         bf16* __restrict__ Vb) {
  __shared__ __align__(16) bf16 As[128][32];
  __shared__ __align__(16) bf16 Bs[128][32];
  const int mat = blockIdx.z;
  const int bn = blockIdx.x * 128, bm = blockIdx.y * 128;
  const bf16* W = WT + (size_t)mat * WELEM;
  const int tid = threadIdx.x, lane = tid & 63, warp = tid >> 6;
  const int fr = lane & 15, quad = lane >> 4;
  const int wr = warp >> 1, wc = warp & 1;

  floatx4 acc[4][4] = {};

  const int srow = tid >> 2, scol = (tid & 3) * 8;
  const bf16* as0 = A + (size_t)(bm + srow) * HID + scol;
  const bf16* as1 = A + (size_t)(bm + 64 + srow) * HID + scol;
  const bf16* bs0 = W + (size_t)(bn + srow) * HID + scol;
  const bf16* bs1 = W + (size_t)(bn + 64 + srow) * HID + scol;
  bf16* la0 = &As[srow][scol];
  bf16* la1 = &As[64 + srow][scol];
  bf16* lb0 = &Bs[srow][scol];
  bf16* lb1 = &Bs[64 + srow][scol];

  for (int k0 = 0; k0 < HID; k0 += 32) {
    ASYNC16(as0 + k0, la0);
    ASYNC16(as1 + k0, la1);
    ASYNC16(bs0 + k0, lb0);
    ASYNC16(bs1 + k0, lb1);
    __syncthreads();
    bf16x8 a[4], b[4];
#pragma unroll
    for (int mi = 0; mi < 4; ++mi) a[mi] = *(const bf16x8*)&As[wr * 64 + mi * 16 + fr][quad * 8];
#pragma unroll
    for (int ni = 0; ni < 4; ++ni) b[ni] = *(const bf16x8*)&Bs[wc * 64 + ni * 16 + fr][quad * 8];
#pragma unroll
    for (int mi = 0; mi < 4; ++mi)
#pragma unroll
      for (int ni = 0; ni < 4; ++ni) acc[mi][ni] = mfma_bf16(a[mi], b[ni], acc[mi][ni]);
    __syncthreads();
  }

  const float* bias = (mat == 0) ? bq : (mat == 1) ? bk : bv;
#pragma unroll
  for (int mi = 0; mi < 4; ++mi)
#pragma unroll
    for (int ni = 0; ni < 4; ++ni)
#pragma unroll
      for (int r = 0; r < 4; ++r) {
        const int grow = bm + wr * 64 + mi * 16 + quad * 4 + r;
        const int gcol = bn + wc * 64 + ni * 16 + fr;
        float v = acc[mi][ni][r] + bias[gcol];
        const int bb = grow >> 10, ss = grow & 1023;
        const int head = gcol >> 6, dc = gcol & 63;
        const size_t bh = (size_t)bb * NHEAD + head;
        const size_t idx = (bh * SEQ + ss) * DHEAD + dc;
        if (mat == 0) Qb[idx] = (bf16)(v * 0.125f);
        else if (mat == 1) Kb[idx] = (bf16)v;
        else Vb[idx] = (bf16)v;
      }
}

// ---------------------------------------------------------------------------
// V transpose+pack: Vb [bh][s][d] -> Vp [bh][d][s'], where within each 32-s
// chunk, position p = g*8+j holds s = (j<4) ? g*4+j : 16+g*4+(j-4).
// One bf16x8 load at p = quad*8 then yields both x16-PV A-fragments.
// ---------------------------------------------------------------------------
__global__ void vtrans(const bf16* __restrict__ Vb, bf16* __restrict__ Vp) {
  __shared__ bf16 t[64][72];
  const int st = blockIdx.x, bh = blockIdx.y;
  const int tid = threadIdx.x;
  const bf16* src = Vb + ((size_t)bh * SEQ + st * 64) * DHEAD;
#pragma unroll
  for (int p = 0; p < 2; ++p) {
    const int r = p * 32 + (tid >> 3), c = (tid & 7) * 8;
    *(bf16x8*)&t[r][c] = *(const bf16x8*)(src + (size_t)r * DHEAD + c);
  }
  __syncthreads();
#pragma unroll
  for (int p = 0; p < 2; ++p) {
    const int d = p * 32 + (tid >> 3);
    const int p0 = (tid & 7) * 8;       // dest position within 64-s tile
    const int cb = p0 & ~31;            // 32-chunk base
    const int g = (p0 >> 3) & 3;
    bf16x8 o;
#pragma unroll
    for (int j = 0; j < 8; ++j) {
      const int k = cb + ((j < 4) ? (g * 4 + j) : (16 + g * 4 + (j - 4)));
      o[j] = t[k][d];
    }
    *(bf16x8*)(Vp + ((size_t)bh * DHEAD + d) * SEQ + st * 64 + p0) = o;
  }
}

// ---------------------------------------------------------------------------
// Attention, head-group split: 1536 blocks, blk = (qt*3+hg)*8 + b so that
// XCD = blk%8 = b (K/V of one batch L2-resident per XCD; 3 hg blocks of a
// (qt,b) are dispatch-adjacent -> their bias line slices merge in that L2).
// Per block: 16 q-rows, 4 heads (1/warp), 32 k-chunks of 32.
// Bias slab/chunk = [16 q][32 k][4 h] fp32 = 8 KB, double-buffered ASYNC16,
// XOR-swizzled units (2-way banks). Mask = bit-words staged once (2 KB).
// Swapped QK^T -> S^T in regs; in-register online softmax; x16 PV from
// packed Vp (one 16B load per dvt). LDS 18.5 KB -> 6 blocks/CU.
// ---------------------------------------------------------------------------
__launch_bounds__(256, 6)
__global__ void attn_kernel(const bf16* __restrict__ Qb, const bf16* __restrict__ Kb,
                            const bf16* __restrict__ Vp, const float* __restrict__ bias,
                            const unsigned int* __restrict__ Mbits,
                            bf16* __restrict__ Ob) {
  __shared__ __align__(16) float4 Bb[2][512]; // bias dbuf, 16 KB
  __shared__ __align__(16) int4 Mw[128];      // mask bit-words, 2 KB

  const int blk = blockIdx.x;
  const int b = blk & 7;
  const int t2 = blk >> 3;
  const int hg = t2 % 3, qt = t2 / 3;

  const int tid = threadIdx.x, lane = tid & 63, warp = tid >> 6;
  const int fr = lane & 15, quad = lane >> 4, f7 = fr & 7;
  const size_t brow = (size_t)b * SEQ + qt * 16;
  const int h = hg * 4 + warp;
  const size_t bh = (size_t)b * NHEAD + h;

  // Q fragments (pre-scaled by 1/8 in qkv_gemm)
  const bf16* Qp = Qb + (bh * SEQ + qt * 16) * DHEAD;
  const bf16x8 qa0 = *(const bf16x8*)(Qp + fr * DHEAD + quad * 8);
  const bf16x8 qa1 = *(const bf16x8*)(Qp + fr * DHEAD + 32 + quad * 8);

  // bias staging sources: LDS unit p holds global (q=p>>5, k=(p&31)^(q&7)),
  // 16B unit = heads [4hg..4hg+3] of one (q,k).
  const float4* bias4 = (const float4*)bias;
  const int p0 = tid, p1 = tid + 256;
  const int q0s = p0 >> 5, k0s = (p0 & 31) ^ (q0s & 7);
  const int q1s = p1 >> 5, k1s = (p1 & 31) ^ (q1s & 7);
  const float4* bsrc0 = bias4 + ((size_t)(brow + q0s) * SEQ + k0s) * 3 + hg;
  const float4* bsrc1 = bias4 + ((size_t)(brow + q1s) * SEQ + k1s) * 3 + hg;

  // prologue: stage chunk 0 bias + all mask bit-words ([16 q][8 int4 units])
  ASYNC16(bsrc0, &Bb[0][p0]);
  ASYNC16(bsrc1, &Bb[0][p1]);
  if (tid < 128) {
    const int mq = tid >> 3, mu = (tid & 7) ^ (mq & 7);
    ASYNC16((const int4*)(Mbits + (size_t)(brow + mq) * 32) + mu, &Mw[tid]);
  }
  __syncthreads();

  const unsigned int* Mwords = (const unsigned int*)Mw;
  float mrun = -1e30f, lrun = 0.f;
  floatx4 oacc[4] = {};

  for (int ch = 0; ch < 32; ++ch) {
    const int c0 = ch * 32;

    // issue next chunk's bias into the other buffer; lands by the barrier
    // at the END of this iteration (compute covers the HBM latency).
    if (ch < 31) {
      float4* Bn = Bb[(ch + 1) & 1];
      ASYNC16(bsrc0 + (ch + 1) * 96, Bn + p0);
      ASYNC16(bsrc1 + (ch + 1) * 96, Bn + p1);
    }

    // swapped QK^T: st[ct][r] = S[k = c0+ct*16+quad*4+r][q = fr]
    floatx4 st[2];
#pragma unroll
    for (int ct = 0; ct < 2; ++ct) {
      const bf16* kp = Kb + (bh * SEQ + c0 + ct * 16 + fr) * DHEAD;
      bf16x8 kf0 = *(const bf16x8*)(kp + quad * 8);
      bf16x8 kf1 = *(const bf16x8*)(kp + 32 + quad * 8);
      floatx4 t = {0.f, 0.f, 0.f, 0.f};
      t = mfma_bf16(kf0, qa0, t);
      t = mfma_bf16(kf1, qa1, t);
      st[ct] = t;
    }

    // bias (XOR-swizzled LDS, 2-way banks) + mask bits
    const float* Bf = (const float*)Bb[ch & 1];
    const unsigned int mword = Mwords[(fr << 5) + (ch ^ (f7 << 2))];
    float s8[8];
#pragma unroll
    for (int ct = 0; ct < 2; ++ct)
#pragma unroll
      for (int r = 0; r < 4; ++r) {
        const int k = ct * 16 + quad * 4 + r;
        const float bv = Bf[((fr << 5) + (k ^ f7)) * 4 + warp];
        s8[ct * 4 + r] = ((mword >> k) & 1u) ? 0.f : (st[ct][r] + bv);
      }

    // in-register online softmax (per q = fr; reduce across quads)
    float mx = mrun;
#pragma unroll
    for (int k = 0; k < 8; ++k) mx = fmaxf(mx, s8[k]);
    mx = fmaxf(mx, __shfl_xor(mx, 16));
    mx = fmaxf(mx, __shfl_xor(mx, 32));
    const float alpha = __expf(mrun - mx);
    float e[8], sum = 0.f;
#pragma unroll
    for (int k = 0; k < 8; ++k) { e[k] = __expf(s8[k] - mx); sum += e[k]; }
    sum += __shfl_xor(sum, 16);
    sum += __shfl_xor(sum, 32);
    lrun = lrun * alpha + sum;
    mrun = mx;
    bf16x4 pa0, pa1;
#pragma unroll
    for (int r = 0; r < 4; ++r) { pa0[r] = (bf16)e[r]; pa1[r] = (bf16)e[4 + r]; }

    // PV: O^T[d][q=fr] += V^T x P^T, one packed 16B V load per dvt
#pragma unroll
    for (int dvt = 0; dvt < 4; ++dvt) {
#pragma unroll
      for (int r = 0; r < 4; ++r) oacc[dvt][r] *= alpha;
      const bf16* vp = Vp + (bh * DHEAD + dvt * 16 + fr) * SEQ + c0 + quad * 8;
      bf16x8 vv = *(const bf16x8*)vp;
      bf16x4 v0 = {vv[0], vv[1], vv[2], vv[3]};   // k = quad*4+0..3   (ct=0)
      bf16x4 v1 = {vv[4], vv[5], vv[6], vv[7]};   // k = 16+quad*4+0..3 (ct=1)
      oacc[dvt] = mfma16_bf16(v0, pa0, oacc[dvt]);
      oacc[dvt] = mfma16_bf16(v1, pa1, oacc[dvt]);
    }

    __syncthreads();  // readers of Bb[cur] done; Bb[nxt] async loads drained
  }

  // epilogue: normalize (per-lane, q = fr) and store
  const float linv = 1.0f / lrun;
#pragma unroll
  for (int dvt = 0; dvt < 4; ++dvt) {
    bf16x4 o;
#pragma unroll
    for (int r = 0; r < 4; ++r) o[r] = (bf16)(oacc[dvt][r] * linv);
    *(bf16x4*)(Ob + (brow + fr) * HID + h * 64 + dvt * 16 + quad * 4) = o;
  }
}

// ---------------------------------------------------------------------------
// Output projection, m97 structure: out = Ob @ Wo + bo (fp32)
// ---------------------------------------------------------------------------
__launch_bounds__(256, 2)
__global__ void out_gemm(const bf16* __restrict__ A, const bf16* __restrict__ W,
                         const float* __restrict__ bo, float* __restrict__ out) {
  __shared__ __align__(16) bf16 As[128][32];
  __shared__ __align__(16) bf16 Bs[128][32];
  const int bn = blockIdx.x * 128, bm = blockIdx.y * 128;
  const int tid = threadIdx.x, lane = tid & 63, warp = tid >> 6;
  const int fr = lane & 15, quad = lane >> 4;
  const int wr = warp >> 1, wc = warp & 1;

  floatx4 acc[4][4] = {};

  const int srow = tid >> 2, scol = (tid & 3) * 8;
  const bf16* as0 = A + (size_t)(bm + srow) * HID + scol;
  const bf16* as1 = A + (size_t)(bm + 64 + srow) * HID + scol;
  const bf16* bs0 = W + (size_t)(bn + srow) * HID + scol;
  const bf16* bs1 = W + (size_t)(bn + 64 + srow) * HID + scol;
  bf16* la0 = &As[srow][scol];
  bf16* la1 = &As[64 + srow][scol];
  bf16* lb0 = &Bs[srow][scol];
  bf16* lb1 = &Bs[64 + srow][scol];

  for (int k0 = 0; k0 < HID; k0 += 32) {
    ASYNC16(as0 + k0, la0);
    ASYNC16(as1 + k0, la1);
    ASYNC16(bs0 + k0, lb0);
    ASYNC16(bs1 + k0, lb1);
    __syncthreads();
    bf16x8 a[4], b[4];
#pragma unroll
    for (int mi = 0; mi < 4; ++mi) a[mi] = *(const bf16x8*)&As[wr * 64 + mi * 16 + fr][quad * 8];
#pragma unroll
    for (int ni = 0; ni < 4; ++ni) b[ni] = *(const bf16x8*)&Bs[wc * 64 + ni * 16 + fr][quad * 8];
#pragma unroll
    for (int mi = 0; mi < 4; ++mi)
#pragma unroll
      for (int ni = 0; ni < 4; ++ni) acc[mi][ni] = mfma_bf16(a[mi], b[ni], acc[mi][ni]);
    __syncthreads();
  }

#pragma unroll
  for (int mi = 0; mi < 4; ++mi)
#pragma unroll
    for (int ni = 0; ni < 4; ++ni)
#pragma unroll
      for (int r = 0; r < 4; ++r) {
        const int grow = bm + wr * 64 + mi * 16 + quad * 4 + r;
        const int gcol = bn + wc * 64 + ni * 16 + fr;
        out[(size_t)grow * HID + gcol] = acc[mi][ni][r] + bo[gcol];
      }
}

// ---------------------------------------------------------------------------
extern "C" void kernel_launch(void* const* d_in, const int* in_sizes, int n_in,
                              void* d_out, int out_size, void* d_ws, size_t ws_size,
                              hipStream_t stream) {
  const float* h  = (const float*)d_in[0];
  const float* ab = (const float*)d_in[1];
  const int*   mk = (const int*)d_in[2];
  const float* Wq = (const float*)d_in[3];
  const float* bq = (const float*)d_in[4];
  const float* Wk = (const float*)d_in[5];
  const float* bk = (const float*)d_in[6];
  const float* Wv = (const float*)d_in[7];
  const float* bv = (const float*)d_in[8];
  const float* Wo = (const float*)d_in[9];
  const float* bo = (const float*)d_in[10];
  float* out = (float*)d_out;

  // ws: bf16 [ WT(4W) | hb | Qb | Kb | Vb | Vp ] then Mbits (uint32, 1 MB).
  bf16* WT = (bf16*)d_ws;
  bf16* hb = WT + (size_t)4 * WELEM;
  bf16* Qb = hb + (size_t)QKVELEM;
  bf16* Kb = Qb + (size_t)QKVELEM;
  bf16* Vb = Kb + (size_t)QKVELEM;
  bf16* Vp = Vb + (size_t)QKVELEM;
  bf16* Ob = Vb;  // reuse (dead after vtrans)
  unsigned int* Mbits = (unsigned int*)(Vp + (size_t)QKVELEM);

  prep_weights<<<dim3(24, 24, 4), dim3(32, 8), 0, stream>>>(Wq, Wk, Wv, Wo, WT);
  prep_h<<<3072, 256, 0, stream>>>(h, hb);
  maskpack<<<1024, 256, 0, stream>>>(mk, Mbits);
  qkv_gemm<<<dim3(6, 64, 3), 256, 0, stream>>>(hb, WT, bq, bk, bv, Qb, Kb, Vb);
  vtrans<<<dim3(16, 96), 256, 0, stream>>>(Vb, Vp);
  attn_kernel<<<1536, 256, 0, stream>>>(Qb, Kb, Vp, ab, Mbits, Ob);
  out_gemm<<<dim3(6, 64), 256, 0, stream>>>(Ob, WT + (size_t)3 * WELEM, bo, out);
}